// Round 6
// baseline (123.781 us; speedup 1.0000x reference)
//
#include <hip/hip_runtime.h>
#include <math.h>

#define TT   4096          // tokens (B*S)
#define HH   4096          // hidden
#define EE   8             // experts
#define KTOP 2
#define CAP  1280          // capacity = int(T*K/E*1.25)
#define TEC  ((size_t)TT * EE * CAP)   // 41,943,040

#define NBLK 4096          // one block per token (gate); also zero grid
#define ASSIGN_BLOCKS 64   // 256 chunks of 32 items; 4 chunks per block

typedef __attribute__((ext_vector_type(4))) float f32x4;

// ---------------- ws layout ----------------
// ws_part: float[NBLK*9]  per-token partials ([0..7]=softmax probs, [8]=logsumexp)
// ws_e:    int[T*K]
// ws_w:    float[T*K]

// Pure-read phase: one block per token; 4 waves split H 4-ways,
// 64-lane butterfly + LDS combine. No output-zeroing here (stream purity).
__global__ __launch_bounds__(256) void gate_kernel(
    const float* __restrict__ x, const float* __restrict__ W,
    float* __restrict__ out, float* __restrict__ ws_part,
    int* __restrict__ ws_e, float* __restrict__ ws_w)
{
    __shared__ float wpart[4][8];

    int tid  = threadIdx.x;
    int wave = tid >> 6;
    int lane = tid & 63;
    int t    = blockIdx.x;

    const float4* __restrict__ X4 = (const float4*)x + (size_t)t * 1024;
    const float4* __restrict__ W4 = (const float4*)W;   // [8][1024]

    float acc[8];
#pragma unroll
    for (int e = 0; e < 8; ++e) acc[e] = 0.f;

#pragma unroll
    for (int j = 0; j < 4; ++j) {
        int ci = wave * 256 + j * 64 + lane;
        float4 xv = X4[ci];
#pragma unroll
        for (int e = 0; e < 8; ++e) {
            float4 wv = W4[e * 1024 + ci];
            acc[e] = fmaf(xv.x, wv.x, acc[e]);
            acc[e] = fmaf(xv.y, wv.y, acc[e]);
            acc[e] = fmaf(xv.z, wv.z, acc[e]);
            acc[e] = fmaf(xv.w, wv.w, acc[e]);
        }
    }

#pragma unroll
    for (int e = 0; e < 8; ++e) {
#pragma unroll
        for (int s = 32; s >= 1; s >>= 1)
            acc[e] += __shfl_xor(acc[e], s, 64);
    }
    if (lane == 0) {
#pragma unroll
        for (int e = 0; e < 8; ++e) wpart[wave][e] = acc[e];
    }
    __syncthreads();

    if (tid == 0) {
        float l[8];
#pragma unroll
        for (int e = 0; e < 8; ++e)
            l[e] = wpart[0][e] + wpart[1][e] + wpart[2][e] + wpart[3][e];

        // full-softmax stats for aux losses
        float m = l[0];
#pragma unroll
        for (int e = 1; e < 8; ++e) m = fmaxf(m, l[e]);
        float p[8], s = 0.f;
#pragma unroll
        for (int e = 0; e < 8; ++e) { p[e] = expf(l[e] - m); s += p[e]; }
        float inv = 1.f / s;
#pragma unroll
        for (int e = 0; e < 8; ++e) ws_part[t * 9 + e] = p[e] * inv;
        ws_part[t * 9 + 8] = m + logf(s);     // logsumexp

        // top-2 (ties -> lowest index)
        int i0 = 0;
#pragma unroll
        for (int e = 1; e < 8; ++e) if (l[e] > l[i0]) i0 = e;
        int i1 = (i0 == 0) ? 1 : 0;
#pragma unroll
        for (int e = 0; e < 8; ++e) if (e != i0 && l[e] > l[i1]) i1 = e;

        float w0 = 1.f / (1.f + expf(l[i1] - l[i0]));
        float w1 = 1.f - w0;

        float* out_topi = out + 2 * TEC;
        out_topi[t * 2 + 0] = (float)i0;
        out_topi[t * 2 + 1] = (float)i1;
        ws_e[t * 2 + 0] = i0;
        ws_e[t * 2 + 1] = i1;
        ws_w[t * 2 + 0] = w0;
        ws_w[t * 2 + 1] = w1;
    }
}

// Pure-write phase: NT fill of out[0, 2*TEC). 80KB contiguous per block.
__global__ __launch_bounds__(256) void zero_kernel(float* __restrict__ out)
{
    int tid = threadIdx.x;
    const int per = (int)((2 * TEC / 4) / NBLK);   // 5120 float4 per block
    f32x4* p = (f32x4*)out + (size_t)blockIdx.x * per;
    f32x4 z = {0.f, 0.f, 0.f, 0.f};
#pragma unroll 4
    for (int i = tid; i < per; i += 256)
        __builtin_nontemporal_store(z, &p[i]);
}

// ASSIGN_BLOCKS blocks x 256 threads. Every block redundantly computes the
// identical per-chunk exclusive prefix counts (32KB L2-resident read), then
// scatters only its own 4 chunks -> scatter spreads over 64 CUs.
// Block 0 also reduces loss partials and writes the 2 scalars.
__global__ __launch_bounds__(256) void assign_kernel(
    const int* __restrict__ ws_e, const float* __restrict__ ws_w,
    const float* __restrict__ ws_part, float* __restrict__ out)
{
    __shared__ int   scnt[256][8];
    __shared__ int   ssum[8][8];     // [segment][expert]
    __shared__ int   stot[8];
    __shared__ float lacc[9];

    int tid = threadIdx.x;
    if (tid < 9) lacc[tid] = 0.f;
    __syncthreads();

    if (blockIdx.x == 0) {
        // reduce 4096 token partials: 16 per thread, registers then LDS atomics
        float r[9];
#pragma unroll
        for (int j = 0; j < 9; ++j) r[j] = 0.f;
        for (int k = 0; k < NBLK / 256; ++k) {
            const float* q = ws_part + (size_t)(tid * (NBLK / 256) + k) * 9;
#pragma unroll
            for (int j = 0; j < 9; ++j) r[j] += q[j];
        }
#pragma unroll
        for (int j = 0; j < 9; ++j) atomicAdd(&lacc[j], r[j]);
    }

    // per-thread expert counts over this thread's 32-item chunk
    const int PER = (TT * KTOP) / 256;   // 32
    int i0 = tid * PER;
    int cnt[8];
#pragma unroll
    for (int e = 0; e < 8; ++e) cnt[e] = 0;
    for (int j = 0; j < PER; ++j) cnt[ws_e[i0 + j]]++;
#pragma unroll
    for (int e = 0; e < 8; ++e) scnt[tid][e] = cnt[e];
    __syncthreads();

    // two-level exclusive scan over 256 chunks, per expert
    if (tid < 64) {                       // 8 segments x 8 experts
        int e = tid & 7, seg = tid >> 3;
        int run = 0;
        for (int j = seg * 32; j < seg * 32 + 32; ++j) {
            int v = scnt[j][e];
            scnt[j][e] = run;
            run += v;
        }
        ssum[seg][e] = run;
    }
    __syncthreads();
    if (tid < 8) {
        int run = 0;
        for (int s = 0; s < 8; ++s) {
            int v = ssum[s][tid];
            ssum[s][tid] = run;
            run += v;
        }
        stot[tid] = run;
    }
    __syncthreads();

    // scatter: block b owns chunks [4b, 4b+4)
    if ((tid >> 2) == blockIdx.x) {
        int seg = tid >> 5;
        int base[8];
#pragma unroll
        for (int e = 0; e < 8; ++e) base[e] = scnt[tid][e] + ssum[seg][e];

        for (int j = 0; j < PER; ++j) {
            int i = i0 + j;
            int e = ws_e[i];
            int pos = base[e]++;
            if (pos < CAP) {
                int tok = i >> 1;
                size_t idx = (size_t)tok * (EE * CAP) + (size_t)e * CAP + pos;
                out[idx] = 1.0f;              // dispatch_mask
                out[TEC + idx] = ws_w[i];     // combine_weights
            }
        }
    }

    if (blockIdx.x == 0 && tid == 0) {
        int tot_valid = 0;
        int ve[8];
#pragma unroll
        for (int e = 0; e < 8; ++e) { ve[e] = min(stot[e], CAP); tot_valid += ve[e]; }
        float lbl = 0.f;
#pragma unroll
        for (int e = 0; e < 8; ++e)
            lbl += (lacc[e] / (float)TT) * ((float)ve[e] / (float)tot_valid);
        lbl *= 0.01f * (float)EE;
        float zl = 0.001f * lacc[8] / (float)TT;
        out[2 * TEC + TT * KTOP + 0] = lbl;
        out[2 * TEC + TT * KTOP + 1] = zl;
    }
}

extern "C" void kernel_launch(void* const* d_in, const int* in_sizes, int n_in,
                              void* d_out, int out_size, void* d_ws, size_t ws_size,
                              hipStream_t stream) {
    const float* x = (const float*)d_in[0];   // [4,1024,4096] -> [T,H]
    const float* W = (const float*)d_in[1];   // [E,H]
    float* out = (float*)d_out;

    float* ws_part = (float*)d_ws;                                   // NBLK*9 floats
    int*   ws_e    = (int*)((char*)d_ws + (size_t)NBLK * 9 * 4);     // T*K ints
    float* ws_w    = (float*)((char*)d_ws + (size_t)NBLK * 9 * 4 + (size_t)TT * KTOP * 4);

    // Phase-pure kernels, stream-serialized: pure-read gate, pure-write zero,
    // then the small scatter. De-mixes HBM read/write streams (r5 post-mortem:
    // mixed traffic ran at ~5 TB/s vs 7 TB/s pure-write fill).
    gate_kernel<<<NBLK, 256, 0, stream>>>(x, W, out, ws_part, ws_e, ws_w);
    zero_kernel<<<NBLK, 256, 0, stream>>>(out);
    assign_kernel<<<ASSIGN_BLOCKS, 256, 0, stream>>>(ws_e, ws_w, ws_part, out);
}

// Round 7
// 113.052 us; speedup vs baseline: 1.0949x; 1.0949x over previous
//
#include <hip/hip_runtime.h>
#include <math.h>

#define TT   4096          // tokens (B*S)
#define HH   4096          // hidden
#define EE   8             // experts
#define KTOP 2
#define CAP  1280          // capacity = int(T*K/E*1.25)
#define TEC  ((size_t)TT * EE * CAP)   // 41,943,040

#define GATE_BLOCKS 1024   // 4 tokens/block, 4 waves split H 4-ways
#define ZS_BLOCKS   4096   // 80KB contiguous zero + <=4 scatter writes each

typedef __attribute__((ext_vector_type(4))) float f32x4;

// ---------------- ws layout ----------------
// ws_part: float[TT*9]   per-token ([0..7]=softmax probs, [8]=logsumexp)
// ws_e:    int[T*K]      expert per flat assignment
// ws_w:    float[T*K]    gate weight per flat assignment
// ws_pos:  int[T*K]      capacity slot, or -1 if dropped

// -------- phase 1: pure-read gate --------
// 1024 blocks x 256. Each block: 4 tokens; each wave covers an H-quarter for
// all 4 tokens (W tile reused across tokens -> W traffic 128MB L2 total).
__global__ __launch_bounds__(256) void gate_kernel(
    const float* __restrict__ x, const float* __restrict__ W,
    float* __restrict__ out, float* __restrict__ ws_part,
    int* __restrict__ ws_e, float* __restrict__ ws_w)
{
    __shared__ float wpart[4][4][8];   // [wave][token][expert]

    int tid  = threadIdx.x;
    int wave = tid >> 6;
    int lane = tid & 63;
    int t0   = blockIdx.x * 4;

    const float4* __restrict__ X4 = (const float4*)x;   // [T][1024]
    const float4* __restrict__ W4 = (const float4*)W;   // [8][1024]

    float acc[4][8];
#pragma unroll
    for (int tt = 0; tt < 4; ++tt)
#pragma unroll
        for (int e = 0; e < 8; ++e) acc[tt][e] = 0.f;

#pragma unroll
    for (int j = 0; j < 4; ++j) {
        int ci = wave * 256 + j * 64 + lane;   // float4 col in [0,1024)
        float4 wv[8];
#pragma unroll
        for (int e = 0; e < 8; ++e) wv[e] = W4[e * 1024 + ci];
#pragma unroll
        for (int tt = 0; tt < 4; ++tt) {
            float4 xv = X4[(size_t)(t0 + tt) * 1024 + ci];
#pragma unroll
            for (int e = 0; e < 8; ++e) {
                acc[tt][e] = fmaf(xv.x, wv[e].x, acc[tt][e]);
                acc[tt][e] = fmaf(xv.y, wv[e].y, acc[tt][e]);
                acc[tt][e] = fmaf(xv.z, wv[e].z, acc[tt][e]);
                acc[tt][e] = fmaf(xv.w, wv[e].w, acc[tt][e]);
            }
        }
    }

    // 64-lane butterfly reduce
#pragma unroll
    for (int tt = 0; tt < 4; ++tt)
#pragma unroll
        for (int e = 0; e < 8; ++e) {
#pragma unroll
            for (int s = 32; s >= 1; s >>= 1)
                acc[tt][e] += __shfl_xor(acc[tt][e], s, 64);
        }

    if (lane == 0) {
#pragma unroll
        for (int tt = 0; tt < 4; ++tt)
#pragma unroll
            for (int e = 0; e < 8; ++e) wpart[wave][tt][e] = acc[tt][e];
    }
    __syncthreads();

    if (tid < 4) {                    // one thread per token
        int t = t0 + tid;
        float l[8];
#pragma unroll
        for (int e = 0; e < 8; ++e)
            l[e] = wpart[0][tid][e] + wpart[1][tid][e] +
                   wpart[2][tid][e] + wpart[3][tid][e];

        // full-softmax stats for aux losses
        float m = l[0];
#pragma unroll
        for (int e = 1; e < 8; ++e) m = fmaxf(m, l[e]);
        float p[8], s = 0.f;
#pragma unroll
        for (int e = 0; e < 8; ++e) { p[e] = expf(l[e] - m); s += p[e]; }
        float inv = 1.f / s;
#pragma unroll
        for (int e = 0; e < 8; ++e) ws_part[t * 9 + e] = p[e] * inv;
        ws_part[t * 9 + 8] = m + logf(s);     // logsumexp

        // top-2 (ties -> lowest index)
        int i0 = 0;
#pragma unroll
        for (int e = 1; e < 8; ++e) if (l[e] > l[i0]) i0 = e;
        int i1 = (i0 == 0) ? 1 : 0;
#pragma unroll
        for (int e = 0; e < 8; ++e) if (e != i0 && l[e] > l[i1]) i1 = e;

        float w0 = 1.f / (1.f + expf(l[i1] - l[i0]));
        float w1 = 1.f - w0;

        float* out_topi = out + 2 * TEC;
        out_topi[t * 2 + 0] = (float)i0;
        out_topi[t * 2 + 1] = (float)i1;
        ws_e[t * 2 + 0] = i0;
        ws_e[t * 2 + 1] = i1;
        ws_w[t * 2 + 0] = w0;
        ws_w[t * 2 + 1] = w1;
    }
}

// -------- phase 2: tiny scan (1 block) --------
// Sequential-semantics capacity positions for all 8192 flat assignments
// (-1 if dropped), plus the 2 loss scalars.
__global__ __launch_bounds__(256) void scan_kernel(
    const int* __restrict__ ws_e, const float* __restrict__ ws_part,
    int* __restrict__ ws_pos, float* __restrict__ out)
{
    __shared__ int   scnt[256][8];
    __shared__ int   ssum[8][8];     // [segment][expert]
    __shared__ int   stot[8];
    __shared__ float lacc[9];

    int tid = threadIdx.x;
    if (tid < 9) lacc[tid] = 0.f;
    __syncthreads();

    // reduce 4096 token partials: 16 rows per thread
    {
        float r[9];
#pragma unroll
        for (int j = 0; j < 9; ++j) r[j] = 0.f;
        for (int k = 0; k < TT / 256; ++k) {
            const float* q = ws_part + (size_t)(tid * (TT / 256) + k) * 9;
#pragma unroll
            for (int j = 0; j < 9; ++j) r[j] += q[j];
        }
#pragma unroll
        for (int j = 0; j < 9; ++j) atomicAdd(&lacc[j], r[j]);
    }

    // per-thread expert counts over this thread's 32-item chunk
    const int PER = (TT * KTOP) / 256;   // 32
    int i0 = tid * PER;
    int cnt[8];
#pragma unroll
    for (int e = 0; e < 8; ++e) cnt[e] = 0;
    for (int j = 0; j < PER; ++j) cnt[ws_e[i0 + j]]++;
#pragma unroll
    for (int e = 0; e < 8; ++e) scnt[tid][e] = cnt[e];
    __syncthreads();

    // two-level exclusive scan over 256 chunks, per expert
    if (tid < 64) {                       // 8 segments x 8 experts
        int e = tid & 7, seg = tid >> 3;
        int run = 0;
        for (int j = seg * 32; j < seg * 32 + 32; ++j) {
            int v = scnt[j][e];
            scnt[j][e] = run;
            run += v;
        }
        ssum[seg][e] = run;
    }
    __syncthreads();
    if (tid < 8) {
        int run = 0;
        for (int s = 0; s < 8; ++s) {
            int v = ssum[s][tid];
            ssum[s][tid] = run;
            run += v;
        }
        stot[tid] = run;
    }
    __syncthreads();

    // replay: write capacity slot (or -1) per assignment
    {
        int seg = tid >> 5;
        int base[8];
#pragma unroll
        for (int e = 0; e < 8; ++e) base[e] = scnt[tid][e] + ssum[seg][e];
        for (int j = 0; j < PER; ++j) {
            int i = i0 + j;
            int e = ws_e[i];
            int pos = base[e]++;
            ws_pos[i] = (pos < CAP) ? pos : -1;
        }
    }

    if (tid == 0) {
        int tot_valid = 0;
        int ve[8];
#pragma unroll
        for (int e = 0; e < 8; ++e) { ve[e] = min(stot[e], CAP); tot_valid += ve[e]; }
        float lbl = 0.f;
#pragma unroll
        for (int e = 0; e < 8; ++e)
            lbl += (lacc[e] / (float)TT) * ((float)ve[e] / (float)tot_valid);
        lbl *= 0.01f * (float)EE;
        float zl = 0.001f * lacc[8] / (float)TT;
        out[2 * TEC + TT * KTOP + 0] = lbl;
        out[2 * TEC + TT * KTOP + 1] = zl;
    }
}

// -------- phase 3: pure-write zero + in-place scatter --------
// 4096 blocks x 256. Block b PLAIN-store zeroes floats [b*20480, (b+1)*20480)
// of out (80KB contiguous = 2 tokens' worth of one region), then overwrites
// the <=4 slots belonging to its 2 tokens. __syncthreads() (drains vmcnt)
// orders the scatter after the zero stores.
__global__ __launch_bounds__(256) void zs_kernel(
    const int* __restrict__ ws_e, const int* __restrict__ ws_pos,
    const float* __restrict__ ws_w, float* __restrict__ out)
{
    int tid = threadIdx.x;
    int b   = blockIdx.x;

    const int per4 = (int)((2 * TEC / 4) / ZS_BLOCKS);   // 5120 float4
    f32x4* p = (f32x4*)out + (size_t)b * per4;
    f32x4 z = {0.f, 0.f, 0.f, 0.f};
#pragma unroll 4
    for (int i = tid; i < per4; i += 256)
        p[i] = z;

    __syncthreads();   // compiler emits s_waitcnt vmcnt(0) before barrier

    if (tid < 4) {
        bool is_mask = (b < ZS_BLOCKS / 2);
        int tbase = is_mask ? 2 * b : 2 * (b - ZS_BLOCKS / 2);
        int lt = tid >> 1, k = tid & 1;
        int i = (tbase + lt) * 2 + k;
        int pos = ws_pos[i];
        if (pos >= 0) {
            int e = ws_e[i];
            float v = is_mask ? 1.0f : ws_w[i];
            float* fp = out + (size_t)b * (per4 * 4);
            fp[lt * (EE * CAP) + e * CAP + pos] = v;
        }
    }
}

extern "C" void kernel_launch(void* const* d_in, const int* in_sizes, int n_in,
                              void* d_out, int out_size, void* d_ws, size_t ws_size,
                              hipStream_t stream) {
    const float* x = (const float*)d_in[0];   // [4,1024,4096] -> [T,H]
    const float* W = (const float*)d_in[1];   // [E,H]
    float* out = (float*)d_out;

    char* ws = (char*)d_ws;
    float* ws_part = (float*)ws;                               // TT*9 floats
    int*   ws_e    = (int*)(ws + (size_t)TT * 9 * 4);          // T*K ints
    float* ws_w    = (float*)(ws + (size_t)TT * 9 * 4 + (size_t)TT * KTOP * 4);
    int*   ws_pos  = (int*)(ws + (size_t)TT * 9 * 4 + (size_t)TT * KTOP * 8);

    gate_kernel<<<GATE_BLOCKS, 256, 0, stream>>>(x, W, out, ws_part, ws_e, ws_w);
    scan_kernel<<<1, 256, 0, stream>>>(ws_e, ws_part, ws_pos, out);
    zs_kernel<<<ZS_BLOCKS, 256, 0, stream>>>(ws_e, ws_pos, ws_w, out);
}